// Round 2
// baseline (613.108 us; speedup 1.0000x reference)
//
#include <hip/hip_runtime.h>
#include <math.h>

#define B_ 16
#define S_ 1024
#define D_ 1024
#define NH_ 16
#define M_TOT (B_ * S_)

typedef __attribute__((ext_vector_type(8))) short short8v;
typedef __attribute__((ext_vector_type(4))) short short4v;
typedef __attribute__((ext_vector_type(4))) float float4v;
typedef __attribute__((ext_vector_type(4))) unsigned int uint4v;

static __device__ __forceinline__ unsigned short f2bf(float f) {
  union { float f; unsigned u; } x; x.f = f;
  unsigned r = (x.u + 0x7fffu + ((x.u >> 16) & 1u)) >> 16;
  return (unsigned short)r;
}
static __device__ __forceinline__ float bf2f(unsigned short u) {
  union { unsigned u; float f; } x; x.u = ((unsigned)u) << 16;
  return x.f;
}

// pack two f32 -> bf16x2 word, RNE (a -> low half).  Manual f2bf (known-RNE):
// round-1 failure (absmax 9.4e-3, ~biased-P signature) implicates
// v_cvt_pk_bf16_f32 rounding mode, so we avoid the packed-convert instr.
static __device__ __forceinline__ unsigned pack2bf(float a, float b) {
  return ((unsigned)f2bf(b) << 16) | (unsigned)f2bf(a);
}

// async global->LDS, 16B per lane; LDS dest = wave-uniform base + lane*16 (m104)
static __device__ __forceinline__ void load_lds16(const unsigned short* g, unsigned short* l) {
  __builtin_amdgcn_global_load_lds(
      (const __attribute__((address_space(1))) unsigned int*)g,
      (__attribute__((address_space(3))) unsigned int*)l, 16, 0, 0);
}

// ---------------------------------------------------------------- RoPE tables
__global__ void build_tables(float* __restrict__ cos1, float* __restrict__ sin1,
                             float* __restrict__ cos2, float* __restrict__ sin2) {
  int t = blockIdx.x * 256 + threadIdx.x;
  if (t < S_ * 8) {
    int s = t >> 3, i = t & 7;
    double ang = (double)s * pow(10000.0, -(double)i / 8.0);
    cos1[t] = (float)cos(ang);
    sin1[t] = (float)sin(ang);
  } else if (t < S_ * 8 + 384) {
    int u = t - S_ * 8;
    int p = u / 12, j = u - p * 12;
    double ang = (double)p * pow(10000.0, -(double)j / 12.0);
    cos2[u] = (float)cos(ang);
    sin2[u] = (float)sin(ang);
  }
}

// ---------------------------------------------------------------- fp32 -> bf16
__global__ __launch_bounds__(256) void f32_to_bf16(
    const float* __restrict__ src, unsigned short* __restrict__ dst, int n4) {
  int i = blockIdx.x * 256 + threadIdx.x;
  if (i < n4) {
    float4 v = ((const float4*)src)[i];
    unsigned short t[4] = {f2bf(v.x), f2bf(v.y), f2bf(v.z), f2bf(v.w)};
    ((short4v*)dst)[i] = *(short4v*)t;
  }
}

// all four 1024x1024 weights in one launch (blockIdx.y selects the matrix)
__global__ __launch_bounds__(256) void w4_to_bf16(
    const float* __restrict__ w0, const float* __restrict__ w1,
    const float* __restrict__ w2, const float* __restrict__ w3,
    unsigned short* __restrict__ dst) {
  const float* srcs[4] = {w0, w1, w2, w3};
  const float* src = srcs[blockIdx.y];
  unsigned short* d = dst + (size_t)blockIdx.y * D_ * D_;
  int i = blockIdx.x * 256 + threadIdx.x;   // < D_*D_/4
  float4 v = ((const float4*)src)[i];
  unsigned short t[4] = {f2bf(v.x), f2bf(v.y), f2bf(v.z), f2bf(v.w)};
  ((short4v*)d)[i] = *(short4v*)t;
}

// ---------------------------------------------------------------- bf16 MFMA GEMM
// C[M,1024] = A[M,1024] @ W[1024,1024]^T + bias.  m97 structure: 128x128 tile,
// BK=32, global_load_lds dwordx4 staging, 8 ds_read_b128 + 16 MFMA /wave/K-step.
// Grid: 1024 linear, swizzled so the 8 bn-blocks sharing an A-tile are within
// 64 CONSECUTIVE ids on ONE XCD (id%8) -> temporal+spatial L2 co-residency.
template <bool BF16OUT>
__global__ __launch_bounds__(256) void gemm_mfma(
    const unsigned short* __restrict__ A, const unsigned short* __restrict__ W,
    const float* __restrict__ bias, void* __restrict__ Cout) {
  __shared__ unsigned short As[128 * 32];   // [row][k] contiguous, no pad (m104)
  __shared__ unsigned short Bs[128 * 32];
  const int t = threadIdx.x;
  const int w = t >> 6, L = t & 63;
  const int c = L & 15, g = L >> 4;
  const int id = blockIdx.x;
  const int xcd = id & 7, slot = id >> 3;
  const int bn = (slot & 7) * 128;
  const int bm = ((slot >> 3) * 8 + xcd) * 128;

  const int srow = w * 32 + (L >> 2);
  const int sko = (L & 3) * 8;
  const unsigned short* gA = A + (size_t)(bm + srow) * D_ + sko;
  const unsigned short* gB = W + (size_t)(bn + srow) * D_ + sko;
  unsigned short* lA = As + w * 1024;
  unsigned short* lB = Bs + w * 1024;

  const int wm = (w >> 1) * 64, wn = (w & 1) * 64;

  float4v acc[4][4];
#pragma unroll
  for (int i = 0; i < 4; ++i)
#pragma unroll
    for (int j = 0; j < 4; ++j) acc[i][j] = (float4v){0.f, 0.f, 0.f, 0.f};

  for (int k0 = 0; k0 < D_; k0 += 32) {
    __syncthreads();
    load_lds16(gA + k0, lA);
    load_lds16(gA + k0 + 16 * D_, lA + 512);
    load_lds16(gB + k0, lB);
    load_lds16(gB + k0 + 16 * D_, lB + 512);
    __syncthreads();
    short8v af[4], bf[4];
#pragma unroll
    for (int i = 0; i < 4; ++i)
      af[i] = *(const short8v*)&As[(wm + 16 * i + c) * 32 + 8 * g];
#pragma unroll
    for (int j = 0; j < 4; ++j)
      bf[j] = *(const short8v*)&Bs[(wn + 16 * j + c) * 32 + 8 * g];
#pragma unroll
    for (int i = 0; i < 4; ++i)
#pragma unroll
      for (int j = 0; j < 4; ++j)
        acc[i][j] = __builtin_amdgcn_mfma_f32_16x16x32_bf16(af[i], bf[j], acc[i][j], 0, 0, 0);
  }
#pragma unroll
  for (int i = 0; i < 4; ++i)
#pragma unroll
    for (int r = 0; r < 4; ++r) {
      const size_t row = (size_t)bm + wm + 16 * i + 4 * g + r;
#pragma unroll
      for (int j = 0; j < 4; ++j) {
        const int col = bn + wn + 16 * j + c;
        float vv = acc[i][j][r] + bias[col];
        if (BF16OUT)
          ((unsigned short*)Cout)[row * D_ + col] = f2bf(vv);
        else
          ((float*)Cout)[row * D_ + col] = vv;
      }
    }
}

// ---------------------------------------------------------------- RoPE in place (bf16)
__global__ __launch_bounds__(256) void rope_inplace(
    unsigned short* q,
    const float* __restrict__ cos1, const float* __restrict__ sin1,
    const float* __restrict__ cos2, const float* __restrict__ sin2,
    float scale) {
  int tid = blockIdx.x * 256 + threadIdx.x;
  int u = tid & 511;
  int m = tid >> 9;
  int s = m & (S_ - 1);
  int head = u >> 5, w = u & 31;
  size_t base = (size_t)m * D_ + head * 64;
  size_t c0, c1;
  float cv, sv;
  if (w < 8) {
    c0 = base + 2 * w; c1 = c0 + 1;
    cv = cos1[s * 8 + w]; sv = sin1[s * 8 + w];
  } else if (w < 20) {
    int j = w - 8, x = s & 31;
    c0 = base + 16 + j; c1 = base + 28 + j;
    cv = cos2[x * 12 + j]; sv = sin2[x * 12 + j];
  } else {
    int j = w - 20, y = s >> 5;
    c0 = base + 40 + j; c1 = base + 52 + j;
    cv = cos2[y * 12 + j]; sv = sin2[y * 12 + j];
  }
  float a = bf2f(q[c0]), b = bf2f(q[c1]);
  q[c0] = f2bf((a * cv - b * sv) * scale);
  q[c1] = f2bf((a * sv + b * cv) * scale);
}

// ---------------------------------------------------------------- V transpose (bf16)
// vb [b][s][head*64+n]  ->  vT [b][head][n(64)][s(1024)]
__global__ __launch_bounds__(256) void v_transpose(
    const unsigned short* __restrict__ v, unsigned short* __restrict__ vT) {
  __shared__ unsigned short T[64][72];
  const int t = threadIdx.x;
  const int st0 = blockIdx.x * 64;
  const int hd = blockIdx.y, b = blockIdx.z;
  const unsigned short* src = v + ((size_t)b * S_ + st0) * D_ + hd * 64;
#pragma unroll
  for (int rep = 0; rep < 4; ++rep) {
    int id = t + rep * 256;
    int s = id >> 4, n4 = (id & 15) * 4;
    short4v val = *(const short4v*)(src + (size_t)s * D_ + n4);
    T[n4 + 0][s] = val[0]; T[n4 + 1][s] = val[1];
    T[n4 + 2][s] = val[2]; T[n4 + 3][s] = val[3];
  }
  __syncthreads();
  unsigned short* dst = vT + ((size_t)(b * NH_ + hd) * 64) * S_ + st0;
#pragma unroll
  for (int rep = 0; rep < 2; ++rep) {
    int id = t + rep * 256;
    int n = id >> 3, s8 = (id & 7) * 8;
    unsigned short tmp[8];
#pragma unroll
    for (int u2 = 0; u2 < 8; ++u2) tmp[u2] = T[n][s8 + u2];
    *(short8v*)(dst + (size_t)n * S_ + s8) = *(short8v*)tmp;
  }
}

// ---------------------------------------------------------------- MFMA flash attention
// grid = 2048 linear, swizzled: xcd=id%8, slot=id/8, qt=slot%8,
// pair=(slot/8)*8+xcd.  The 8 qt-blocks of a pair occupy 64 CONSECUTIVE ids on
// ONE XCD -> K/V (256 KB/pair) L2-resident while all its readers run.
//
// Swapped QK^T (T12 pattern): sacc[i][j] = mfma(K, Q) so lane (c,g) holds
// S[q=16i+c][k=16j+4g+r] -- softmax is lane-local, P never touches LDS.
// P -> bf16 pairs via manual-RNE pack; A-fragment redistribution via
// ds_bpermute (fixed permutation: word q2 of ap[i][st] = pk[i][2st+(g>>1)][q2&1]
// pulled from lane 16*(2*(g&1)+(q2>>1))+c).
// K is single-buffered: next tile's K loads issue right after QK MFMAs consume
// the registers; softmax+PV (~500cy) hides the L2 latency.
__global__ __launch_bounds__(256) void attn_mfma(
    const unsigned short* __restrict__ qb, const unsigned short* __restrict__ kb,
    const unsigned short* __restrict__ vT, unsigned short* __restrict__ out) {
  const int t = threadIdx.x;
  const int w = t >> 6;
  const int L = t & 63;
  const int c = L & 15;
  const int g = L >> 4;
  const int id = blockIdx.x;
  const int xcd = id & 7, slot = id >> 3;
  const int qt = slot & 7;
  const int pair = (slot >> 3) * 8 + xcd;
  const int b = pair >> 4, hd = pair & 15;
  const size_t mrow0 = (size_t)b * S_ + qt * 128 + w * 32;
  const int dcol0 = hd * 64;

  // bpermute pull addresses (byte = 4*src_lane)
  const int a_lo = (((L & 16) ? 32 : 0) + c) * 4;  // src g = 2*(g&1)
  const int a_hi = a_lo + 64;                      // src g = 2*(g&1)+1
  const bool ghi = (L >= 32);                      // g>=2 -> wants j = 2st+1

  short8v aq[2][2];
#pragma unroll
  for (int i = 0; i < 2; ++i)
#pragma unroll
    for (int st = 0; st < 2; ++st)
      aq[i][st] = *(const short8v*)(qb + (mrow0 + 16 * i + c) * D_ + dcol0 + 32 * st + 8 * g);

  float4v oacc[2][4];
  float lsum[2] = {0.f, 0.f};
#pragma unroll
  for (int i = 0; i < 2; ++i)
#pragma unroll
    for (int jv = 0; jv < 4; ++jv) oacc[i][jv] = (float4v){0.f, 0.f, 0.f, 0.f};

  const unsigned short* vbase = vT + (size_t)(b * NH_ + hd) * 64 * S_;
  const unsigned short* kbb = kb + (size_t)b * S_ * D_ + dcol0;

  short8v kf[4][2];
#pragma unroll
  for (int j = 0; j < 4; ++j) {
    const unsigned short* kr = kbb + (size_t)(16 * j + c) * D_ + 8 * g;
    kf[j][0] = *(const short8v*)(kr);
    kf[j][1] = *(const short8v*)(kr + 32);
  }

#pragma unroll 2
  for (int kt = 0; kt < 16; ++kt) {
    // S^T = K*Q^T : lane (c,g) holds S[q=16i+c][k=16j+4g+r]
    float4v sacc[2][4];
#pragma unroll
    for (int i = 0; i < 2; ++i)
#pragma unroll
      for (int j = 0; j < 4; ++j) sacc[i][j] = (float4v){0.f, 0.f, 0.f, 0.f};
#pragma unroll
    for (int j = 0; j < 4; ++j)
#pragma unroll
      for (int i = 0; i < 2; ++i) {
        sacc[i][j] = __builtin_amdgcn_mfma_f32_16x16x32_bf16(kf[j][0], aq[i][0], sacc[i][j], 0, 0, 0);
        sacc[i][j] = __builtin_amdgcn_mfma_f32_16x16x32_bf16(kf[j][1], aq[i][1], sacc[i][j], 0, 0, 0);
      }
    // kf registers dead -> prefetch next K tile into them
    if (kt < 15) {
#pragma unroll
      for (int j = 0; j < 4; ++j) {
        const unsigned short* kr = kbb + (size_t)((kt + 1) * 64 + 16 * j + c) * D_ + 8 * g;
        kf[j][0] = *(const short8v*)(kr);
        kf[j][1] = *(const short8v*)(kr + 32);
      }
    }
    // V fragments for this tile (consumed after softmax -> latency hidden)
    short8v vf[4][2];
#pragma unroll
    for (int jv = 0; jv < 4; ++jv) {
      const unsigned short* vr = vbase + (size_t)(16 * jv + c) * S_ + kt * 64 + 8 * g;
      vf[jv][0] = *(const short8v*)(vr);
      vf[jv][1] = *(const short8v*)(vr + 32);
    }
    // in-register softmax: exp + lane-local row-sum + pack pairs to bf16 (RNE)
    unsigned pk[2][4][2];
#pragma unroll
    for (int i = 0; i < 2; ++i)
#pragma unroll
      for (int j = 0; j < 4; ++j) {
        float p0 = __expf(sacc[i][j][0]);
        float p1 = __expf(sacc[i][j][1]);
        float p2 = __expf(sacc[i][j][2]);
        float p3 = __expf(sacc[i][j][3]);
        lsum[i] += (p0 + p1) + (p2 + p3);
        pk[i][j][0] = pack2bf(p0, p1);
        pk[i][j][1] = pack2bf(p2, p3);
      }
    // redistribute: ap[i][st] elem 8g+u = P[q=16i+c][k=32st+8g+u]
    short8v ap[2][2];
#pragma unroll
    for (int i = 0; i < 2; ++i)
#pragma unroll
      for (int st = 0; st < 2; ++st) {
        uint4v wv;
#pragma unroll
        for (int q2 = 0; q2 < 4; ++q2) {
          const int addr = (q2 & 2) ? a_hi : a_lo;
          int vlo = __builtin_amdgcn_ds_bpermute(addr, (int)pk[i][2 * st][q2 & 1]);
          int vhi = __builtin_amdgcn_ds_bpermute(addr, (int)pk[i][2 * st + 1][q2 & 1]);
          wv[q2] = (unsigned)(ghi ? vhi : vlo);
        }
        ap[i][st] = *(short8v*)&wv;
      }
#pragma unroll
    for (int jv = 0; jv < 4; ++jv)
#pragma unroll
      for (int i = 0; i < 2; ++i) {
        oacc[i][jv] = __builtin_amdgcn_mfma_f32_16x16x32_bf16(ap[i][0], vf[jv][0], oacc[i][jv], 0, 0, 0);
        oacc[i][jv] = __builtin_amdgcn_mfma_f32_16x16x32_bf16(ap[i][1], vf[jv][1], oacc[i][jv], 0, 0, 0);
      }
  }
#pragma unroll
  for (int i = 0; i < 2; ++i) {
    float ls = lsum[i];
    ls += __shfl_xor(ls, 16);
    ls += __shfl_xor(ls, 32);
#pragma unroll
    for (int r = 0; r < 4; ++r) {
      // output row q=16i+4g+r; its denominator lives at lane 4g+r (c=4g+r,g=0)
      float inv = 1.f / __shfl(ls, 4 * g + r);
      size_t row = mrow0 + 16 * i + 4 * g + r;
#pragma unroll
      for (int jv = 0; jv < 4; ++jv)
        out[row * D_ + dcol0 + 16 * jv + c] = f2bf(oacc[i][jv][r] * inv);
    }
  }
}

// ---------------------------------------------------------------- launch
// Workspace (peak 168.03 MB < 192 MB proven):
//   [0,32)MB xb (reused as ob after QKV gemms) | [32,64) qb | [64,96) kb
//   [96,128) vb | [128,160) vT | [160,168) wqb,wkb,wvb,wob | [168,+32KB) tables
extern "C" void kernel_launch(void* const* d_in, const int* in_sizes, int n_in,
                              void* d_out, int out_size, void* d_ws, size_t ws_size,
                              hipStream_t stream) {
  const float* x  = (const float*)d_in[0];
  const float* Wq = (const float*)d_in[1];
  const float* bq = (const float*)d_in[2];
  const float* Wk = (const float*)d_in[3];
  const float* bk = (const float*)d_in[4];
  const float* Wv = (const float*)d_in[5];
  const float* bv = (const float*)d_in[6];
  const float* Wo = (const float*)d_in[7];
  const float* bo = (const float*)d_in[8];
  float* out = (float*)d_out;

  char* ws = (char*)d_ws;
  const size_t SZ2 = (size_t)M_TOT * D_ * 2;   // 32 MB
  unsigned short* xb = (unsigned short*)(ws);
  unsigned short* ob = xb;                               // alias: free after QKV gemms
  unsigned short* qb = (unsigned short*)(ws + SZ2);
  unsigned short* kb = (unsigned short*)(ws + 2 * SZ2);
  unsigned short* vb = (unsigned short*)(ws + 3 * SZ2);
  unsigned short* vT = (unsigned short*)(ws + 4 * SZ2);
  unsigned short* wqb = (unsigned short*)(ws + 5 * SZ2);
  unsigned short* wkb = wqb + (size_t)D_ * D_;
  unsigned short* wvb = wkb + (size_t)D_ * D_;
  unsigned short* wob = wvb + (size_t)D_ * D_;
  float* cos1 = (float*)(ws + 5 * SZ2 + 4 * (size_t)D_ * D_ * 2);
  float* sin1 = cos1 + S_ * 8;
  float* cos2 = sin1 + S_ * 8;
  float* sin2 = cos2 + 384;

  build_tables<<<34, 256, 0, stream>>>(cos1, sin1, cos2, sin2);

  f32_to_bf16<<<M_TOT * D_ / 4 / 256, 256, 0, stream>>>(x, xb, M_TOT * D_ / 4);
  w4_to_bf16<<<dim3(D_ * D_ / 4 / 256, 4), 256, 0, stream>>>(Wq, Wk, Wv, Wo, wqb);

  gemm_mfma<true><<<1024, 256, 0, stream>>>(xb, wqb, bq, qb);
  gemm_mfma<true><<<1024, 256, 0, stream>>>(xb, wkb, bk, kb);
  gemm_mfma<true><<<1024, 256, 0, stream>>>(xb, wvb, bv, vb);

  const int rope_blocks = (M_TOT * 512) / 256;
  rope_inplace<<<rope_blocks, 256, 0, stream>>>(qb, cos1, sin1, cos2, sin2, 0.125f);
  rope_inplace<<<rope_blocks, 256, 0, stream>>>(kb, cos1, sin1, cos2, sin2, 1.0f);
  v_transpose<<<dim3(16, 16, 16), 256, 0, stream>>>(vb, vT);

  attn_mfma<<<2048, 256, 0, stream>>>(qb, kb, vT, ob);

  gemm_mfma<false><<<1024, 256, 0, stream>>>(ob, wob, bo, out);
}